// Round 12
// baseline (151.879 us; speedup 1.0000x reference)
//
#include <hip/hip_runtime.h>
#include <math.h>

// flash-decode, GQA paged KV. R=4, B=16, Hq=32, Hk=8 (G=4), D=128, P=8192,
// PAGE=1, M=2048.
// Storage (confirmed round 7): q/k_cache/v_cache FLOAT32; lens/bt int32;
// out float32.
//
// Round 12: fold all 4 GQA heads into each wave (4 q-frags + 4 accs); the
// 4 waves of a block cover one 32-token window per iteration in disjoint
// interleaved 8-token strips. This removes the 4x redundant K/V loads of
// r8/r11 (4x fewer VMEM instrs) and quadruples compute per load batch so
// the A/B register pipeline finally covers load latency. Softmax rescale
// branch-deferred (exact). Split-KV S=16, log2-domain.

typedef float f32x4 __attribute__((ext_vector_type(4)));

#define R_ 4
#define B_ 16
#define HQ_ 32
#define HK_ 8
#define G_ 4
#define D_ 128
#define P_ 8192
#define M_ 2048
#define HKD (HK_ * D_)
#define SC2 (0.08838834764831845f * 1.4426950408889634f)  // scale * log2(e)

__device__ __forceinline__ void load8f(const float* p, float o[8]) {
  f32x4 a = *(const f32x4*)p;
  f32x4 b = *(const f32x4*)(p + 4);
#pragma unroll
  for (int j = 0; j < 4; ++j) { o[j] = a[j]; o[4 + j] = b[j]; }
}

__device__ __forceinline__ int clampP(int p) {
  return p < 0 ? 0 : (p >= P_ ? P_ - 1 : p);
}

// ---------------- kernel 1: per-(r,b,hk,split) partials ----------------
__global__ __launch_bounds__(256) void fd_partial(
    const float* __restrict__ q, const float* __restrict__ kc,
    const float* __restrict__ vc, const int* __restrict__ lens,
    const int* __restrict__ bt, float* __restrict__ ws_m,
    float* __restrict__ ws_l, float* __restrict__ ws_o, int S) {
  const int idx = blockIdx.x;
  const int s = idx % S;
  const int hk = (idx / S) % HK_;
  const int b = (idx / (S * HK_)) % B_;
  const int r = idx / (S * HK_ * B_);

  const int lane = threadIdx.x & 63;
  const int w = threadIdx.x >> 6;  // wave id -> 8-token strip in each window
  const int tg = lane >> 4;        // slot 0..3 (2 tokens per slot per iter)
  const int ds = (lane & 15) * 8;  // dim slice [ds, ds+8)
  const int rec = blockIdx.x;      // == ((r*B+b)*HK + hk)*S + s

  int kvlen = lens[r * B_ + b];
  if (kvlen < 0) kvlen = 0;
  if (kvlen > M_) kvlen = M_;
  const int chunk = (kvlen + S - 1) / S;
  const int t0 = s * chunk;
  int t1 = t0 + chunk;
  if (t1 > kvlen) t1 = kvlen;
  if (t0 >= t1) {  // empty split (block-uniform): invalidate all 4 heads
    if (lane == 0) ws_m[rec * G_ + w] = -INFINITY;
    return;
  }

  // q fragments for all 4 heads, pre-scaled into log2 domain
  float qf[G_][8];
  {
    const float* qp = q + (size_t)(b * HQ_ + hk * G_) * D_ + ds;
#pragma unroll
    for (int h = 0; h < G_; ++h) {
      load8f(qp + h * D_, qf[h]);
#pragma unroll
      for (int j = 0; j < 8; ++j) qf[h][j] *= SC2;
    }
  }

  const int* btrow = bt + (r * B_ + b) * M_;
  const float* kb = kc + (size_t)r * P_ * HKD + (size_t)hk * D_ + ds;
  const float* vb = vc + (size_t)r * P_ * HKD + (size_t)hk * D_ + ds;

  // slot-local state, per head
  float m[G_], l[G_], acc[G_][8];
#pragma unroll
  for (int h = 0; h < G_; ++h) {
    m[h] = -INFINITY;
    l[h] = 0.f;
#pragma unroll
    for (int j = 0; j < 8; ++j) acc[h][j] = 0.f;
  }

  const int tmax = t1 - 1;
  auto ti = [&](int t) { return t > tmax ? tmax : t; };

  // this wave-slot's token pair at window i: base + i*32 and base + i*32 + 4
  const int base = t0 + w * 8 + tg;

  auto compute = [&](int tb, const float(&k0)[8], const float(&k1)[8],
                     const float(&v0)[8], const float(&v1)[8]) {
    const bool vld0 = tb < t1;
    const bool vld1 = (tb + 4) < t1;
    float d0[G_], d1[G_];
#pragma unroll
    for (int h = 0; h < G_; ++h) {
      float a0 = 0.f, a1 = 0.f;
#pragma unroll
      for (int j = 0; j < 8; ++j) {
        a0 += qf[h][j] * k0[j];
        a1 += qf[h][j] * k1[j];
      }
      d0[h] = a0;
      d1[h] = a1;
    }
#pragma unroll
    for (int msk = 1; msk <= 8; msk <<= 1) {
#pragma unroll
      for (int h = 0; h < G_; ++h) {
        d0[h] += __shfl_xor(d0[h], msk);
        d1[h] += __shfl_xor(d1[h], msk);
      }
    }
#pragma unroll
    for (int h = 0; h < G_; ++h) {
      const float s0 = vld0 ? d0[h] : -INFINITY;
      const float s1 = vld1 ? d1[h] : -INFINITY;
      const float mt = fmaxf(s0, s1);
      if (mt > -INFINITY) {                  // slot-uniform
        if (mt > m[h]) {                     // deferred rescale (exact)
          const float sc = exp2f(m[h] - mt); // m=-inf -> 0
          l[h] *= sc;
#pragma unroll
          for (int j = 0; j < 8; ++j) acc[h][j] *= sc;
          m[h] = mt;
        }
        const float p0 = exp2f(s0 - m[h]);   // -inf -> 0
        const float p1 = exp2f(s1 - m[h]);
        l[h] += p0 + p1;
#pragma unroll
        for (int j = 0; j < 8; ++j)
          acc[h][j] += p0 * v0[j] + p1 * v1[j];
      }
    }
  };

  // A/B register pipeline; pages prefetched 2 windows ahead
  float k0A[8], k1A[8], v0A[8], v1A[8];
  float k0B[8], k1B[8], v0B[8], v1B[8];
  int pA0 = clampP(btrow[ti(base)]);
  int pA1 = clampP(btrow[ti(base + 4)]);
  load8f(kb + (size_t)pA0 * HKD, k0A);
  load8f(kb + (size_t)pA1 * HKD, k1A);
  load8f(vb + (size_t)pA0 * HKD, v0A);
  load8f(vb + (size_t)pA1 * HKD, v1A);
  int pB0 = clampP(btrow[ti(base + 32)]);
  int pB1 = clampP(btrow[ti(base + 36)]);

  const int nIter = (t1 - t0 + 31) >> 5;
  for (int i = 0; i < nIter; i += 2) {
    const int tb = base + i * 32;
    {  // window i: consume A, issue B loads (pages ready), refill A-pages
      load8f(kb + (size_t)pB0 * HKD, k0B);
      load8f(kb + (size_t)pB1 * HKD, k1B);
      load8f(vb + (size_t)pB0 * HKD, v0B);
      load8f(vb + (size_t)pB1 * HKD, v1B);
      pA0 = clampP(btrow[ti(tb + 64)]);
      pA1 = clampP(btrow[ti(tb + 68)]);
      compute(tb, k0A, k1A, v0A, v1A);
    }
    if (i + 1 < nIter) {  // window i+1: consume B, issue A, refill B-pages
      load8f(kb + (size_t)pA0 * HKD, k0A);
      load8f(kb + (size_t)pA1 * HKD, k1A);
      load8f(vb + (size_t)pA0 * HKD, v0A);
      load8f(vb + (size_t)pA1 * HKD, v1A);
      pB0 = clampP(btrow[ti(tb + 96)]);
      pB1 = clampP(btrow[ti(tb + 100)]);
      compute(tb + 32, k0B, k1B, v0B, v1B);
    }
  }

  // merge the 4 token slots (xor 16, 32), per head
#pragma unroll
  for (int h = 0; h < G_; ++h) {
#pragma unroll
    for (int off = 16; off <= 32; off <<= 1) {
      const float mo = __shfl_xor(m[h], off);
      const float lo = __shfl_xor(l[h], off);
      float ao[8];
#pragma unroll
      for (int j = 0; j < 8; ++j) ao[j] = __shfl_xor(acc[h][j], off);
      const float mn = fmaxf(m[h], mo);
      const float se = (m[h] > -INFINITY) ? exp2f(m[h] - mn) : 0.f;
      const float so_ = (mo > -INFINITY) ? exp2f(mo - mn) : 0.f;
      l[h] = l[h] * se + lo * so_;
#pragma unroll
      for (int j = 0; j < 8; ++j) acc[h][j] = acc[h][j] * se + ao[j] * so_;
      m[h] = mn;
    }
  }

  // cross-wave merge via LDS; wave w finalizes head g = w
  __shared__ float sm[4][G_], sl[4][G_], so[4][G_][D_ + 4];
  if (lane < 16) {
#pragma unroll
    for (int h = 0; h < G_; ++h) {
#pragma unroll
      for (int j = 0; j < 8; ++j) so[w][h][ds + j] = acc[h][j];
    }
    if (lane == 0) {
#pragma unroll
      for (int h = 0; h < G_; ++h) {
        sm[w][h] = m[h];
        sl[w][h] = l[h];
      }
    }
  }
  __syncthreads();

  const int g = w;
  const float mw0 = sm[0][g], mw1 = sm[1][g], mw2 = sm[2][g], mw3 = sm[3][g];
  const float mf = fmaxf(fmaxf(mw0, mw1), fmaxf(mw2, mw3));
  // mf finite: wave 0 slot 0 always holds token t0
  const float wt0 = (mw0 > -INFINITY) ? exp2f(mw0 - mf) : 0.f;
  const float wt1 = (mw1 > -INFINITY) ? exp2f(mw1 - mf) : 0.f;
  const float wt2 = (mw2 > -INFINITY) ? exp2f(mw2 - mf) : 0.f;
  const float wt3 = (mw3 > -INFINITY) ? exp2f(mw3 - mf) : 0.f;
  const float lf =
      wt0 * sl[0][g] + wt1 * sl[1][g] + wt2 * sl[2][g] + wt3 * sl[3][g];
  const float of0 = wt0 * so[0][g][lane] + wt1 * so[1][g][lane] +
                    wt2 * so[2][g][lane] + wt3 * so[3][g][lane];
  const float of1 = wt0 * so[0][g][lane + 64] + wt1 * so[1][g][lane + 64] +
                    wt2 * so[2][g][lane + 64] + wt3 * so[3][g][lane + 64];
  ws_o[((size_t)rec * G_ + g) * D_ + lane] = of0;
  ws_o[((size_t)rec * G_ + g) * D_ + lane + 64] = of1;
  if (lane == 0) {
    ws_m[rec * G_ + g] = mf;  // log2-domain
    ws_l[rec * G_ + g] = lf;
  }
}

// ---------------- kernel 2: LSE-weighted combine over R*S ----------------
__global__ __launch_bounds__(128) void fd_reduce(
    const float* __restrict__ ws_m, const float* __restrict__ ws_l,
    const float* __restrict__ ws_o, float* __restrict__ out, int S) {
  const int row = blockIdx.x;  // (b*HK + hk)*G + g
  const int g = row % G_;
  const int hk = (row / G_) % HK_;
  const int b = row / (G_ * HK_);
  const int d = threadIdx.x;

  float mf = -INFINITY;
  for (int r = 0; r < R_; ++r)
    for (int s = 0; s < S; ++s) {
      int rec = ((r * B_ + b) * HK_ + hk) * S + s;
      mf = fmaxf(mf, ws_m[rec * G_ + g]);
    }
  float of = 0.f, lf = 0.f;
  for (int r = 0; r < R_; ++r)
    for (int s = 0; s < S; ++s) {
      int rec = ((r * B_ + b) * HK_ + hk) * S + s;
      float wm = ws_m[rec * G_ + g];
      if (wm == -INFINITY) continue;
      float wt = exp2f(wm - mf);  // log2-domain partials
      of += wt * ws_o[((size_t)rec * G_ + g) * D_ + d];
      lf += wt * ws_l[rec * G_ + g];
    }
  out[(size_t)(b * HQ_ + hk * G_ + g) * D_ + d] = of / lf;
}

// ---------------- fallback: monolithic (tiny workspace) ----------------
__global__ __launch_bounds__(256) void fd_mono(
    const float* __restrict__ q, const float* __restrict__ kc,
    const float* __restrict__ vc, const int* __restrict__ lens,
    const int* __restrict__ bt, float* __restrict__ out) {
  const int hk = blockIdx.x % HK_;
  const int b = blockIdx.x / HK_;
  const int lane = threadIdx.x & 63;
  const int g = threadIdx.x >> 6;
  const int tg = lane >> 4;
  const int ds = (lane & 15) * 8;

  float qf[8];
  load8f(q + (size_t)(b * HQ_ + hk * G_ + g) * D_ + ds, qf);

  float m = -INFINITY, l = 0.f, acc[8];
#pragma unroll
  for (int j = 0; j < 8; ++j) acc[j] = 0.f;

  for (int r = 0; r < R_; ++r) {
    int kvlen = lens[r * B_ + b];
    if (kvlen < 0) kvlen = 0;
    if (kvlen > M_) kvlen = M_;
    const int* btrow = bt + (r * B_ + b) * M_;
    const float* kb = kc + (size_t)r * P_ * HKD + (size_t)hk * D_ + ds;
    const float* vb = vc + (size_t)r * P_ * HKD + (size_t)hk * D_ + ds;

    for (int t = 0; t < kvlen; t += 4) {
      const int ta = t + tg;
      const bool va = ta < kvlen;
      const int pga = clampP(btrow[va ? ta : 0]);
      const size_t offa = (size_t)pga * HKD;
      float ka[8], wa[8];
      load8f(kb + offa, ka);
      load8f(vb + offa, wa);

      float da = 0.f;
#pragma unroll
      for (int j = 0; j < 8; ++j) da += qf[j] * ka[j];
#pragma unroll
      for (int msk = 1; msk <= 8; msk <<= 1) da += __shfl_xor(da, msk);

      const float sa = va ? da * SC2 : -INFINITY;
      const float mn = fmaxf(m, sa);
      if (mn > -INFINITY) {
        const float sc = exp2f(m - mn);
        const float pa = exp2f(sa - mn);
        m = mn;
        l = l * sc + pa;
#pragma unroll
        for (int j = 0; j < 8; ++j) acc[j] = acc[j] * sc + pa * wa[j];
      }
    }
  }

#pragma unroll
  for (int off = 16; off <= 32; off <<= 1) {
    const float mo = __shfl_xor(m, off);
    const float lo = __shfl_xor(l, off);
    float ao[8];
#pragma unroll
    for (int j = 0; j < 8; ++j) ao[j] = __shfl_xor(acc[j], off);
    const float mn = fmaxf(m, mo);
    const float se = (m > -INFINITY) ? exp2f(m - mn) : 0.f;
    const float so_ = (mo > -INFINITY) ? exp2f(mo - mn) : 0.f;
    l = l * se + lo * so_;
#pragma unroll
    for (int j = 0; j < 8; ++j) acc[j] = acc[j] * se + ao[j] * so_;
    m = mn;
  }

  if (lane < 16) {
    float inv = (l > 0.f) ? 1.0f / l : 0.f;
#pragma unroll
    for (int j = 0; j < 8; ++j)
      out[(size_t)(b * HQ_ + hk * G_ + g) * D_ + ds + j] = acc[j] * inv;
  }
}

extern "C" void kernel_launch(void* const* d_in, const int* in_sizes, int n_in,
                              void* d_out, int out_size, void* d_ws,
                              size_t ws_size, hipStream_t stream) {
  const float* q = (const float*)d_in[0];
  const float* kc = (const float*)d_in[1];
  const float* vc = (const float*)d_in[2];
  const int* lens = (const int*)d_in[3];
  const int* bt = (const int*)d_in[4];
  float* out = (float*)d_out;

  auto need = [](int s) {
    return (size_t)R_ * B_ * HK_ * s * (size_t)(2 * G_ + G_ * D_) *
           sizeof(float);
  };
  int S = 16;
  while (S > 1 && need(S) > ws_size) S >>= 1;

  if (need(S) <= ws_size) {
    const int nrec = R_ * B_ * HK_ * S;
    float* ws_m = (float*)d_ws;
    float* ws_l = ws_m + (size_t)nrec * G_;
    float* ws_o = ws_l + (size_t)nrec * G_;
    fd_partial<<<nrec, 256, 0, stream>>>(q, kc, vc, lens, bt, ws_m, ws_l,
                                         ws_o, S);
    fd_reduce<<<B_ * HK_ * G_, 128, 0, stream>>>(ws_m, ws_l, ws_o, out, S);
  } else {
    fd_mono<<<B_ * HK_, 256, 0, stream>>>(q, kc, vc, lens, bt, out);
  }
}

// Round 13
// 99.397 us; speedup vs baseline: 1.5280x; 1.5280x over previous
//
#include <hip/hip_runtime.h>
#include <math.h>

// flash-decode, GQA paged KV. R=4, B=16, Hq=32, Hk=8 (G=4), D=128, P=8192,
// PAGE=1, M=2048.
// Storage (confirmed round 7): q/k_cache/v_cache FLOAT32; lens/bt int32;
// out float32.
//
// Round 13: S=4 (longer blocks; r12's S=16 blocks were ~70% prologue/
// epilogue at 21% occupancy), 4-token batches per slot (softmax update
// amortized; one int4 page load per slot per window), finite -1e30
// sentinels -> fully branchless softmax, 32-bit byte offsets with
// wave-uniform base (saddr-form loads).

typedef float f32x4 __attribute__((ext_vector_type(4)));

#define R_ 4
#define B_ 16
#define HQ_ 32
#define HK_ 8
#define G_ 4
#define D_ 128
#define P_ 8192
#define M_ 2048
#define HKD (HK_ * D_)
#define SC2 (0.08838834764831845f * 1.4426950408889634f)  // scale * log2(e)
#define MNEG (-1.0e30f)

__device__ __forceinline__ void load8u(const float* __restrict__ ubase,
                                       unsigned boff, float o[8]) {
  const f32x4* p = (const f32x4*)((const char*)ubase + boff);
  f32x4 a = p[0];
  f32x4 b = p[1];
#pragma unroll
  for (int j = 0; j < 4; ++j) { o[j] = a[j]; o[4 + j] = b[j]; }
}

__device__ __forceinline__ int clampP(int p) {
  return p < 0 ? 0 : (p >= P_ ? P_ - 1 : p);
}

// ---------------- kernel 1: per-(r,b,hk,split) partials ----------------
__global__ __launch_bounds__(256) void fd_partial(
    const float* __restrict__ q, const float* __restrict__ kc,
    const float* __restrict__ vc, const int* __restrict__ lens,
    const int* __restrict__ bt, float* __restrict__ ws_m,
    float* __restrict__ ws_l, float* __restrict__ ws_o, int S) {
  const int idx = blockIdx.x;
  const int s = idx % S;
  const int hk = (idx / S) % HK_;
  const int b = (idx / (S * HK_)) % B_;
  const int r = idx / (S * HK_ * B_);

  const int lane = threadIdx.x & 63;
  const int w = threadIdx.x >> 6;   // wave id -> 16-token strip per window
  const int tg = lane >> 4;         // slot 0..3: 4 contiguous tokens each
  const int ds = (lane & 15) * 8;   // dim slice [ds, ds+8)
  const unsigned dsb = ds * 4u;     // byte offset of dim slice
  const int rec = blockIdx.x;       // == ((r*B+b)*HK + hk)*S + s

  int kvlen = lens[r * B_ + b];
  if (kvlen < 0) kvlen = 0;
  if (kvlen > M_) kvlen = M_;
  const int chunk = (((kvlen + S - 1) / S) + 63) & ~63;  // 64-aligned
  const int t0 = s * chunk;
  int t1 = t0 + chunk;
  if (t1 > kvlen) t1 = kvlen;
  if (t0 >= t1) {  // empty split: finite sentinel, weight 0 in reduce
    if (lane == 0) ws_m[rec * G_ + w] = MNEG;
    return;
  }

  // q fragments for all 4 heads, pre-scaled into log2 domain
  float qf[G_][8];
  {
    const float* qp = q + (size_t)(b * HQ_ + hk * G_) * D_ + ds;
#pragma unroll
    for (int h = 0; h < G_; ++h) {
      load8u(qp + h * D_, 0u, qf[h]);
#pragma unroll
      for (int j = 0; j < 8; ++j) qf[h][j] *= SC2;
    }
  }

  const int* btrow = bt + (r * B_ + b) * M_;
  // wave-uniform bases; per-lane dim slice folded into the 32-bit offset
  const float* kb = kc + (size_t)r * P_ * HKD + (size_t)hk * D_;
  const float* vb = vc + (size_t)r * P_ * HKD + (size_t)hk * D_;

  float m[G_], l[G_], acc[G_][8];
#pragma unroll
  for (int h = 0; h < G_; ++h) {
    m[h] = MNEG;
    l[h] = 0.f;
#pragma unroll
    for (int j = 0; j < 8; ++j) acc[h][j] = 0.f;
  }

  const int nIter = (t1 - t0 + 63) >> 6;
  const int sbase = t0 + w * 16 + tg * 4;  // 4-aligned, < t0+chunk <= M

  int4 pgN = *(const int4*)(btrow + sbase);

  for (int i = 0; i < nIter; ++i) {
    const int4 pg = pgN;
    if (i + 1 < nIter) pgN = *(const int4*)(btrow + sbase + (i + 1) * 64);
    const unsigned o0 = ((unsigned)clampP(pg.x) << 12) + dsb;
    const unsigned o1 = ((unsigned)clampP(pg.y) << 12) + dsb;
    const unsigned o2 = ((unsigned)clampP(pg.z) << 12) + dsb;
    const unsigned o3 = ((unsigned)clampP(pg.w) << 12) + dsb;

    float k0[8], k1[8], k2[8], k3[8], v0[8], v1[8], v2[8], v3[8];
    load8u(kb, o0, k0);
    load8u(kb, o1, k1);
    load8u(kb, o2, k2);
    load8u(kb, o3, k3);
    load8u(vb, o0, v0);
    load8u(vb, o1, v1);
    load8u(vb, o2, v2);
    load8u(vb, o3, v3);

    float d0[G_], d1[G_], d2[G_], d3[G_];
#pragma unroll
    for (int h = 0; h < G_; ++h) {
      float a0 = 0.f, a1 = 0.f, a2 = 0.f, a3 = 0.f;
#pragma unroll
      for (int j = 0; j < 8; ++j) {
        a0 += qf[h][j] * k0[j];
        a1 += qf[h][j] * k1[j];
        a2 += qf[h][j] * k2[j];
        a3 += qf[h][j] * k3[j];
      }
      d0[h] = a0; d1[h] = a1; d2[h] = a2; d3[h] = a3;
    }
#pragma unroll
    for (int msk = 1; msk <= 8; msk <<= 1) {
#pragma unroll
      for (int h = 0; h < G_; ++h) {
        d0[h] += __shfl_xor(d0[h], msk);
        d1[h] += __shfl_xor(d1[h], msk);
        d2[h] += __shfl_xor(d2[h], msk);
        d3[h] += __shfl_xor(d3[h], msk);
      }
    }

    const int tb = sbase + i * 64;
    const bool va0 = tb < t1;
    const bool va1 = tb + 1 < t1;
    const bool va2 = tb + 2 < t1;
    const bool va3 = tb + 3 < t1;
#pragma unroll
    for (int h = 0; h < G_; ++h) {
      const float s0 = va0 ? d0[h] : -INFINITY;
      const float s1 = va1 ? d1[h] : -INFINITY;
      const float s2 = va2 ? d2[h] : -INFINITY;
      const float s3 = va3 ? d3[h] : -INFINITY;
      const float mt = fmaxf(fmaxf(s0, s1), fmaxf(s2, s3));
      const float mn = fmaxf(m[h], mt);      // finite always (>= MNEG)
      const float sc = exp2f(m[h] - mn);     // branchless, no NaN
      const float p0 = exp2f(s0 - mn);       // -inf -> 0
      const float p1 = exp2f(s1 - mn);
      const float p2 = exp2f(s2 - mn);
      const float p3 = exp2f(s3 - mn);
      m[h] = mn;
      l[h] = l[h] * sc + (p0 + p1) + (p2 + p3);
#pragma unroll
      for (int j = 0; j < 8; ++j)
        acc[h][j] = acc[h][j] * sc + p0 * v0[j] + p1 * v1[j] + p2 * v2[j] +
                    p3 * v3[j];
    }
  }

  // merge the 4 token slots (xor 16, 32), per head — branchless (finite m)
#pragma unroll
  for (int h = 0; h < G_; ++h) {
#pragma unroll
    for (int off = 16; off <= 32; off <<= 1) {
      const float mo = __shfl_xor(m[h], off);
      const float lo = __shfl_xor(l[h], off);
      float ao[8];
#pragma unroll
      for (int j = 0; j < 8; ++j) ao[j] = __shfl_xor(acc[h][j], off);
      const float mn = fmaxf(m[h], mo);
      const float se = exp2f(m[h] - mn);
      const float so_ = exp2f(mo - mn);
      l[h] = l[h] * se + lo * so_;
#pragma unroll
      for (int j = 0; j < 8; ++j) acc[h][j] = acc[h][j] * se + ao[j] * so_;
      m[h] = mn;
    }
  }

  // cross-wave merge via LDS; wave w finalizes head g = w
  __shared__ float sm[4][G_], sl[4][G_], so[4][G_][D_ + 4];
  if (lane < 16) {
#pragma unroll
    for (int h = 0; h < G_; ++h) {
#pragma unroll
      for (int j = 0; j < 8; ++j) so[w][h][ds + j] = acc[h][j];
    }
    if (lane == 0) {
#pragma unroll
      for (int h = 0; h < G_; ++h) {
        sm[w][h] = m[h];
        sl[w][h] = l[h];
      }
    }
  }
  __syncthreads();

  const int g = w;
  const float mw0 = sm[0][g], mw1 = sm[1][g], mw2 = sm[2][g], mw3 = sm[3][g];
  const float mf = fmaxf(fmaxf(mw0, mw1), fmaxf(mw2, mw3));
  const float wt0 = exp2f(mw0 - mf);
  const float wt1 = exp2f(mw1 - mf);
  const float wt2 = exp2f(mw2 - mf);
  const float wt3 = exp2f(mw3 - mf);
  const float lf =
      wt0 * sl[0][g] + wt1 * sl[1][g] + wt2 * sl[2][g] + wt3 * sl[3][g];
  const float of0 = wt0 * so[0][g][lane] + wt1 * so[1][g][lane] +
                    wt2 * so[2][g][lane] + wt3 * so[3][g][lane];
  const float of1 = wt0 * so[0][g][lane + 64] + wt1 * so[1][g][lane + 64] +
                    wt2 * so[2][g][lane + 64] + wt3 * so[3][g][lane + 64];
  ws_o[((size_t)rec * G_ + g) * D_ + lane] = of0;
  ws_o[((size_t)rec * G_ + g) * D_ + lane + 64] = of1;
  if (lane == 0) {
    ws_m[rec * G_ + g] = mf;  // log2-domain
    ws_l[rec * G_ + g] = lf;
  }
}

// ---------------- kernel 2: LSE-weighted combine over R*S ----------------
__global__ __launch_bounds__(128) void fd_reduce(
    const float* __restrict__ ws_m, const float* __restrict__ ws_l,
    const float* __restrict__ ws_o, float* __restrict__ out, int S) {
  const int row = blockIdx.x;  // (b*HK + hk)*G + g
  const int g = row % G_;
  const int hk = (row / G_) % HK_;
  const int b = row / (G_ * HK_);
  const int d = threadIdx.x;

  float mf = MNEG;
  for (int r = 0; r < R_; ++r)
    for (int s = 0; s < S; ++s) {
      int rec = ((r * B_ + b) * HK_ + hk) * S + s;
      mf = fmaxf(mf, ws_m[rec * G_ + g]);
    }
  float of = 0.f, lf = 0.f;
  for (int r = 0; r < R_; ++r)
    for (int s = 0; s < S; ++s) {
      int rec = ((r * B_ + b) * HK_ + hk) * S + s;
      float wt = exp2f(ws_m[rec * G_ + g] - mf);  // empty split -> 0
      of += wt * ws_o[((size_t)rec * G_ + g) * D_ + d];
      lf += wt * ws_l[rec * G_ + g];
    }
  out[(size_t)(b * HQ_ + hk * G_ + g) * D_ + d] = of / lf;
}

// ---------------- fallback: monolithic (tiny workspace) ----------------
__global__ __launch_bounds__(256) void fd_mono(
    const float* __restrict__ q, const float* __restrict__ kc,
    const float* __restrict__ vc, const int* __restrict__ lens,
    const int* __restrict__ bt, float* __restrict__ out) {
  const int hk = blockIdx.x % HK_;
  const int b = blockIdx.x / HK_;
  const int lane = threadIdx.x & 63;
  const int g = threadIdx.x >> 6;
  const int tg = lane >> 4;
  const int ds = (lane & 15) * 8;
  const unsigned dsb = ds * 4u;

  float qf[8];
  load8u(q + (size_t)(b * HQ_ + hk * G_ + g) * D_ + ds, 0u, qf);
#pragma unroll
  for (int j = 0; j < 8; ++j) qf[j] *= SC2;

  float m = MNEG, l = 0.f, acc[8];
#pragma unroll
  for (int j = 0; j < 8; ++j) acc[j] = 0.f;

  for (int r = 0; r < R_; ++r) {
    int kvlen = lens[r * B_ + b];
    if (kvlen < 0) kvlen = 0;
    if (kvlen > M_) kvlen = M_;
    const int* btrow = bt + (r * B_ + b) * M_;
    const float* kb = kc + (size_t)r * P_ * HKD + (size_t)hk * D_;
    const float* vb = vc + (size_t)r * P_ * HKD + (size_t)hk * D_;

    for (int t = 0; t < kvlen; t += 4) {
      const int ta = t + tg;
      const bool va = ta < kvlen;
      const unsigned oa = ((unsigned)clampP(btrow[va ? ta : 0]) << 12) + dsb;
      float ka[8], wa[8];
      load8u(kb, oa, ka);
      load8u(vb, oa, wa);

      float da = 0.f;
#pragma unroll
      for (int j = 0; j < 8; ++j) da += qf[j] * ka[j];
#pragma unroll
      for (int msk = 1; msk <= 8; msk <<= 1) da += __shfl_xor(da, msk);

      const float sa = va ? da : -INFINITY;
      const float mn = fmaxf(m, sa);
      const float sc = exp2f(m - mn);
      const float pa = exp2f(sa - mn);
      m = mn;
      l = l * sc + pa;
#pragma unroll
      for (int j = 0; j < 8; ++j) acc[j] = acc[j] * sc + pa * wa[j];
    }
  }

#pragma unroll
  for (int off = 16; off <= 32; off <<= 1) {
    const float mo = __shfl_xor(m, off);
    const float lo = __shfl_xor(l, off);
    float ao[8];
#pragma unroll
    for (int j = 0; j < 8; ++j) ao[j] = __shfl_xor(acc[j], off);
    const float mn = fmaxf(m, mo);
    const float se = exp2f(m - mn);
    const float so_ = exp2f(mo - mn);
    l = l * se + lo * so_;
#pragma unroll
    for (int j = 0; j < 8; ++j) acc[j] = acc[j] * se + ao[j] * so_;
    m = mn;
  }

  if (lane < 16) {
    float inv = (l > 0.f) ? 1.0f / l : 0.f;
#pragma unroll
    for (int j = 0; j < 8; ++j)
      out[(size_t)(b * HQ_ + hk * G_ + g) * D_ + ds + j] = acc[j] * inv;
  }
}

extern "C" void kernel_launch(void* const* d_in, const int* in_sizes, int n_in,
                              void* d_out, int out_size, void* d_ws,
                              size_t ws_size, hipStream_t stream) {
  const float* q = (const float*)d_in[0];
  const float* kc = (const float*)d_in[1];
  const float* vc = (const float*)d_in[2];
  const int* lens = (const int*)d_in[3];
  const int* bt = (const int*)d_in[4];
  float* out = (float*)d_out;

  auto need = [](int s) {
    return (size_t)R_ * B_ * HK_ * s * (size_t)(2 * G_ + G_ * D_) *
           sizeof(float);
  };
  int S = 4;
  while (S > 1 && need(S) > ws_size) S >>= 1;

  if (need(S) <= ws_size) {
    const int nrec = R_ * B_ * HK_ * S;
    float* ws_m = (float*)d_ws;
    float* ws_l = ws_m + (size_t)nrec * G_;
    float* ws_o = ws_l + (size_t)nrec * G_;
    fd_partial<<<nrec, 256, 0, stream>>>(q, kc, vc, lens, bt, ws_m, ws_l,
                                         ws_o, S);
    fd_reduce<<<B_ * HK_ * G_, 128, 0, stream>>>(ws_m, ws_l, ws_o, out, S);
  } else {
    fd_mono<<<B_ * HK_, 256, 0, stream>>>(q, kc, vc, lens, bt, out);
  }
}